// Round 2
// baseline (6857.715 us; speedup 1.0000x reference)
//
#include <hip/hip_runtime.h>
#include <math.h>

#define NN      100000
#define EE      1600000
#define NPAIRS  800000
#define DIN     128
#define CC      16
#define NITERS  5

// ---------------------------------------------------------------------------
// helpers: bf16 <-> f32
// ---------------------------------------------------------------------------
__device__ __forceinline__ unsigned short f2bf(float f) {
    unsigned int u = __float_as_uint(f);
    unsigned int r = u + 0x7fffu + ((u >> 16) & 1u);   // round-nearest-even
    return (unsigned short)(r >> 16);
}
__device__ __forceinline__ unsigned int pack_bf(float lo, float hi) {
    return (unsigned int)f2bf(lo) | ((unsigned int)f2bf(hi) << 16);
}
__device__ __forceinline__ void unpack8(uint4 u, float* o) {
    o[0] = __uint_as_float(u.x << 16); o[1] = __uint_as_float(u.x & 0xffff0000u);
    o[2] = __uint_as_float(u.y << 16); o[3] = __uint_as_float(u.y & 0xffff0000u);
    o[4] = __uint_as_float(u.z << 16); o[5] = __uint_as_float(u.z & 0xffff0000u);
    o[6] = __uint_as_float(u.w << 16); o[7] = __uint_as_float(u.w & 0xffff0000u);
}

// ---------------------------------------------------------------------------
// log_b0 = log_softmax(x @ W + b)   — 16 lanes per node (lane = class)
// ---------------------------------------------------------------------------
__global__ __launch_bounds__(256) void k_logb0(
    const float* __restrict__ x, const float* __restrict__ W,
    const float* __restrict__ b, float* __restrict__ logb0)
{
    int idx  = blockIdx.x * blockDim.x + threadIdx.x;
    int node = idx >> 4;
    int c    = idx & 15;
    if (node >= NN) return;
    const float* xr = x + (long)node * DIN;
    float acc = b[c];
#pragma unroll 8
    for (int k = 0; k < DIN; ++k)
        acc = fmaf(xr[k], W[k * CC + c], acc);
    float m = acc;
    for (int off = 8; off; off >>= 1) m = fmaxf(m, __shfl_xor(m, off, 16));
    float s = __expf(acc - m);
    for (int off = 8; off; off >>= 1) s += __shfl_xor(s, off, 16);
    logb0[idx] = acc - m - __logf(s);
}

// ---------------------------------------------------------------------------
// M = exp(logH) = sigmoid(10*param), symmetric 16x16 (linear-space coupling)
// ---------------------------------------------------------------------------
__global__ void k_M(const float* __restrict__ param, float* __restrict__ M)
{
    int i = threadIdx.x;
    if (i >= CC * (CC + 1) / 2) return;
    int r = 0;
    while ((r + 1) * (r + 2) / 2 <= i) ++r;
    int c = i - r * (r + 1) / 2;
    float z = param[i] * 10.0f;
    float s = 1.0f / (1.0f + __expf(-z));    // exp(log_sigmoid(z)) == sigmoid(z)
    M[r * CC + c] = s;
    if (r != c) M[c * CC + r] = s;
}

// ---------------------------------------------------------------------------
// init: msg(bf16) = -log(C), agg = 0
// ---------------------------------------------------------------------------
__global__ void k_init(unsigned int* __restrict__ msg32, float* __restrict__ agg)
{
    const float NEGLOGC = -2.772588722239781f;
    unsigned int v = pack_bf(NEGLOGC, NEGLOGC);
    long stride = (long)gridDim.x * blockDim.x;
    long i0 = (long)blockIdx.x * blockDim.x + threadIdx.x;
    for (long j = i0; j < (long)EE * CC / 2; j += stride) msg32[j] = v;
    for (long j = i0; j < (long)NN * CC; j += stride) agg[j] = 0.f;
}

// ---------------------------------------------------------------------------
// message update + scatter, ONE LANE PER EDGE-PAIR, linear-space matvec.
// rv[2p] = 2p+1 structurally (edges 2i,2i+1 are reciprocal) -> no rv load,
// and the in-place msg update is race-free (lane owns both rows).
// ---------------------------------------------------------------------------
__global__ __launch_bounds__(256) void k_edges(
    const int* __restrict__ esrc, const int* __restrict__ edst,
    const float* __restrict__ logb, const float* __restrict__ Mg,
    unsigned short* __restrict__ msg, float* __restrict__ agg)
{
    __shared__ float sM[CC * CC];
    sM[threadIdx.x] = Mg[threadIdx.x];          // blockDim == 256
    __syncthreads();

    int p = blockIdx.x * blockDim.x + threadIdx.x;
    if (p >= NPAIRS) return;
    long e0 = 2L * p;

    int2 s01 = *(const int2*)(esrc + e0);
    int2 d01 = *(const int2*)(edst + e0);

    // old messages for the pair: rows e0, e1 (64B contiguous, bf16)
    const uint4* mp = (const uint4*)(msg + e0 * CC);
    float mo0[16], mo1[16];
    unpack8(mp[0], mo0); unpack8(mp[1], mo0 + 8);
    unpack8(mp[2], mo1); unpack8(mp[3], mo1 + 8);

    // beliefs at the two sources
    float b0v[16], b1v[16];
    {
        const float4* pb0 = (const float4*)(logb + (long)s01.x * CC);
        const float4* pb1 = (const float4*)(logb + (long)s01.y * CC);
        *(float4*)(b0v + 0) = pb0[0]; *(float4*)(b0v + 4)  = pb0[1];
        *(float4*)(b0v + 8) = pb0[2]; *(float4*)(b0v + 12) = pb0[3];
        *(float4*)(b1v + 0) = pb1[0]; *(float4*)(b1v + 4)  = pb1[1];
        *(float4*)(b1v + 8) = pb1[2]; *(float4*)(b1v + 12) = pb1[3];
    }

    // t0 = logb[s0] - msg[e1] ; t1 = logb[s1] - msg[e0]  (rv is pair-swap)
    float p0[16], p1[16];
    float mt0 = -INFINITY, mt1 = -INFINITY;
#pragma unroll
    for (int k = 0; k < CC; ++k) {
        float t0 = b0v[k] - mo1[k];
        float t1 = b1v[k] - mo0[k];
        p0[k] = t0; p1[k] = t1;
        mt0 = fmaxf(mt0, t0); mt1 = fmaxf(mt1, t1);
    }
#pragma unroll
    for (int k = 0; k < CC; ++k) {
        p0[k] = __expf(p0[k] - mt0);
        p1[k] = __expf(p1[k] - mt1);
    }

    // S[c] = sum_k p[k] * M[k][c]  (M rows broadcast from LDS)
    float S0[16], S1[16];
#pragma unroll
    for (int c = 0; c < CC; ++c) { S0[c] = 0.f; S1[c] = 0.f; }
    const float4* sM4 = (const float4*)sM;
#pragma unroll
    for (int k = 0; k < CC; ++k) {
        float mr[16];
        *(float4*)(mr + 0)  = sM4[4 * k + 0];
        *(float4*)(mr + 4)  = sM4[4 * k + 1];
        *(float4*)(mr + 8)  = sM4[4 * k + 2];
        *(float4*)(mr + 12) = sM4[4 * k + 3];
        float a = p0[k], bb = p1[k];
#pragma unroll
        for (int c = 0; c < CC; ++c) {
            S0[c] = fmaf(a,  mr[c], S0[c]);
            S1[c] = fmaf(bb, mr[c], S1[c]);
        }
    }

    // normalized message: log S[c] - log(sum_c S[c])   (mt cancels exactly)
    float T0 = 0.f, T1 = 0.f;
#pragma unroll
    for (int c = 0; c < CC; ++c) { T0 += S0[c]; T1 += S1[c]; }
    float lT0 = __logf(T0), lT1 = __logf(T1);
    float n0[16], n1[16];
#pragma unroll
    for (int c = 0; c < CC; ++c) {
        n0[c] = __logf(S0[c]) - lT0;
        n1[c] = __logf(S1[c]) - lT1;
    }

    // store new messages (bf16, 64B contiguous per lane)
    uint4 w0, w1, w2, w3;
    w0.x = pack_bf(n0[0],  n0[1]);  w0.y = pack_bf(n0[2],  n0[3]);
    w0.z = pack_bf(n0[4],  n0[5]);  w0.w = pack_bf(n0[6],  n0[7]);
    w1.x = pack_bf(n0[8],  n0[9]);  w1.y = pack_bf(n0[10], n0[11]);
    w1.z = pack_bf(n0[12], n0[13]); w1.w = pack_bf(n0[14], n0[15]);
    w2.x = pack_bf(n1[0],  n1[1]);  w2.y = pack_bf(n1[2],  n1[3]);
    w2.z = pack_bf(n1[4],  n1[5]);  w2.w = pack_bf(n1[6],  n1[7]);
    w3.x = pack_bf(n1[8],  n1[9]);  w3.y = pack_bf(n1[10], n1[11]);
    w3.z = pack_bf(n1[12], n1[13]); w3.w = pack_bf(n1[14], n1[15]);
    uint4* mw = (uint4*)(msg + e0 * CC);
    mw[0] = w0; mw[1] = w1; mw[2] = w2; mw[3] = w3;

    // scatter-add into destination nodes
    float* A0 = agg + (long)d01.x * CC;
    float* A1 = agg + (long)d01.y * CC;
#pragma unroll
    for (int c = 0; c < CC; ++c) atomicAdd(A0 + c, n0[c]);
#pragma unroll
    for (int c = 0; c < CC; ++c) atomicAdd(A1 + c, n1[c]);
}

// ---------------------------------------------------------------------------
// log_b = log_normalize(agg + log_b0); also resets agg for next iteration
// ---------------------------------------------------------------------------
__global__ __launch_bounds__(256) void k_update(
    const float* __restrict__ logb0, float* __restrict__ agg,
    float* __restrict__ out)
{
    int idx  = blockIdx.x * blockDim.x + threadIdx.x;
    int node = idx >> 4;
    if (node >= NN) return;
    float v = agg[idx] + logb0[idx];
    agg[idx] = 0.f;
    float m = v;
    for (int off = 8; off; off >>= 1) m = fmaxf(m, __shfl_xor(m, off, 16));
    float s = __expf(v - m);
    for (int off = 8; off; off >>= 1) s += __shfl_xor(s, off, 16);
    out[idx] = v - m - __logf(s);
}

// ---------------------------------------------------------------------------
extern "C" void kernel_launch(void* const* d_in, const int* in_sizes, int n_in,
                              void* d_out, int out_size, void* d_ws, size_t ws_size,
                              hipStream_t stream)
{
    const float* x     = (const float*)d_in[0];
    const float* W     = (const float*)d_in[1];
    const float* b     = (const float*)d_in[2];
    const float* param = (const float*)d_in[3];
    const int*   eidx  = (const int*)d_in[4];
    const int*   esrc  = eidx;
    const int*   edst  = eidx + EE;

    float* ws    = (float*)d_ws;
    float* M     = ws;                         // 256 floats
    float* logb0 = M     + 256;                // N*C
    float* logb  = logb0 + (long)NN * CC;      // N*C
    float* agg   = logb  + (long)NN * CC;      // N*C
    unsigned short* msg = (unsigned short*)(agg + (long)NN * CC);  // E*C bf16

    k_logb0<<<(NN * CC + 255) / 256, 256, 0, stream>>>(x, W, b, logb0);
    k_M    <<<1, 256, 0, stream>>>(param, M);
    k_init <<<2048, 256, 0, stream>>>((unsigned int*)msg, agg);

    const float* curb = logb0;
    for (int it = 0; it < NITERS; ++it) {
        k_edges<<<NPAIRS / 256, 256, 0, stream>>>(esrc, edst, curb, M, msg, agg);
        float* dst = (it == NITERS - 1) ? (float*)d_out : logb;
        k_update<<<(NN * CC + 255) / 256, 256, 0, stream>>>(logb0, agg, dst);
        curb = dst;
    }
}

// Round 4
// 615.937 us; speedup vs baseline: 11.1338x; 11.1338x over previous
//
#include <hip/hip_runtime.h>
#include <math.h>

#define NN      100000
#define EE      1600000
#define NPAIRS  800000
#define DIN     128
#define CC      16
#define NITERS  5
#define PPT     4                    // pairs per thread-group
#define NGRP    (NPAIRS / PPT)       // 200000 groups of 16 lanes

// ---------------------------------------------------------------------------
// helpers: bf16 <-> f32
// ---------------------------------------------------------------------------
__device__ __forceinline__ unsigned short f2bf(float f) {
    unsigned int u = __float_as_uint(f);
    unsigned int r = u + 0x7fffu + ((u >> 16) & 1u);   // round-nearest-even
    return (unsigned short)(r >> 16);
}
__device__ __forceinline__ unsigned int pack_bf(float lo, float hi) {
    return (unsigned int)f2bf(lo) | ((unsigned int)f2bf(hi) << 16);
}

// ---------------------------------------------------------------------------
// log_b0 = log_softmax(x @ W + b)   — 16 lanes per node (lane = class)
// ---------------------------------------------------------------------------
__global__ __launch_bounds__(256) void k_logb0(
    const float* __restrict__ x, const float* __restrict__ W,
    const float* __restrict__ b, float* __restrict__ logb0)
{
    int idx  = blockIdx.x * blockDim.x + threadIdx.x;
    int node = idx >> 4;
    int c    = idx & 15;
    if (node >= NN) return;
    const float* xr = x + (long)node * DIN;
    float acc = b[c];
#pragma unroll 8
    for (int k = 0; k < DIN; ++k)
        acc = fmaf(xr[k], W[k * CC + c], acc);
    float m = acc;
    for (int off = 8; off; off >>= 1) m = fmaxf(m, __shfl_xor(m, off, 16));
    float s = __expf(acc - m);
    for (int off = 8; off; off >>= 1) s += __shfl_xor(s, off, 16);
    logb0[idx] = acc - m - __logf(s);
}

// ---------------------------------------------------------------------------
// M = exp(logH) = sigmoid(10*param), symmetric 16x16 (linear-space coupling)
// ---------------------------------------------------------------------------
__global__ void k_M(const float* __restrict__ param, float* __restrict__ M)
{
    int i = threadIdx.x;
    if (i >= CC * (CC + 1) / 2) return;
    int r = 0;
    while ((r + 1) * (r + 2) / 2 <= i) ++r;
    int c = i - r * (r + 1) / 2;
    float z = param[i] * 10.0f;
    float s = 1.0f / (1.0f + __expf(-z));
    M[r * CC + c] = s;
    if (r != c) M[c * CC + r] = s;
}

// ---------------------------------------------------------------------------
// init: msg2 (u32 = bf16 pair {e0,e1}) = pack(-log C, -log C), agg = 0
// ---------------------------------------------------------------------------
__global__ void k_init(unsigned int* __restrict__ msg2, float* __restrict__ agg)
{
    const float NEGLOGC = -2.772588722239781f;
    unsigned int v = pack_bf(NEGLOGC, NEGLOGC);
    long stride = (long)gridDim.x * blockDim.x;
    long i0 = (long)blockIdx.x * blockDim.x + threadIdx.x;
    for (long j = i0; j < (long)NPAIRS * CC; j += stride) msg2[j] = v;
    for (long j = i0; j < (long)NN * CC; j += stride) agg[j] = 0.f;
}

// ---------------------------------------------------------------------------
// message update + scatter. 16 lanes per edge-pair (lane = class): coalesced
// msg I/O and coalesced 64B atomic scatter. Linear-space matvec:
//   S[c] = sum_k exp(t[k]) * M[k][c];  log_msg[c] = log S[c] - log(sum_c S[c])
// No max-subtraction needed: t_max >= -log C (log_b normalized, msg <= 0) and
// t <= ~7 (msg >= log(M_min/C)), so exp(t) is fp32-safe and S >= ~6e-4.
// msg2[p*16+c] packs both directions of pair p as bf16 {lo=edge 2p, hi=2p+1};
// rv is the pair-swap permutation so the reverse message is the other half.
// ---------------------------------------------------------------------------
__global__ __launch_bounds__(256) void k_edges(
    const int* __restrict__ esrc, const int* __restrict__ edst,
    const float* __restrict__ logb, const float* __restrict__ Mg,
    unsigned int* __restrict__ msg2, float* __restrict__ agg)
{
    __shared__ float sM[CC * CC];
    __shared__ float sE[16 * 40];        // per-group exp-vector staging (stride 40: 2-way max bank alias)
    sM[threadIdx.x] = Mg[threadIdx.x];   // blockDim == 256
    __syncthreads();

    const int lane = threadIdx.x & 15;
    const int gl   = threadIdx.x >> 4;           // group within block (0..15)
    const int g    = blockIdx.x * 16 + gl;       // global group
    float* eb = sE + gl * 40;

    float Hrow[CC];                              // M[k][lane] (symmetric)
#pragma unroll
    for (int k = 0; k < CC; ++k) Hrow[k] = sM[k * CC + lane];

#pragma unroll
    for (int r = 0; r < PPT; ++r) {
        const long p  = (long)g + (long)r * NGRP;
        const long e0 = 2 * p;

        int2 s01 = *(const int2*)(esrc + e0);    // broadcast within group
        int2 d01 = *(const int2*)(edst + e0);

        unsigned int mold = msg2[p * CC + lane];
        float mo0 = __uint_as_float(mold << 16);         // msg[2p][lane]
        float mo1 = __uint_as_float(mold & 0xffff0000u); // msg[2p+1][lane]

        // t = logb[src] - msg[reverse]; reverse of 2p is 2p+1 and vice versa
        float t0 = logb[(long)s01.x * CC + lane] - mo1;
        float t1 = logb[(long)s01.y * CC + lane] - mo0;

        eb[lane]      = __expf(t0);
        eb[16 + lane] = __expf(t1);
        float ev0[CC], ev1[CC];
        *(float4*)(ev0 +  0) = *(const float4*)(eb +  0);
        *(float4*)(ev0 +  4) = *(const float4*)(eb +  4);
        *(float4*)(ev0 +  8) = *(const float4*)(eb +  8);
        *(float4*)(ev0 + 12) = *(const float4*)(eb + 12);
        *(float4*)(ev1 +  0) = *(const float4*)(eb + 16);
        *(float4*)(ev1 +  4) = *(const float4*)(eb + 20);
        *(float4*)(ev1 +  8) = *(const float4*)(eb + 24);
        *(float4*)(ev1 + 12) = *(const float4*)(eb + 28);

        float S0 = 0.f, S1 = 0.f;
#pragma unroll
        for (int k = 0; k < CC; ++k) {
            S0 = fmaf(ev0[k], Hrow[k], S0);
            S1 = fmaf(ev1[k], Hrow[k], S1);
        }

        float T0 = S0, T1 = S1;
        for (int off = 8; off; off >>= 1) {
            T0 += __shfl_xor(T0, off, 16);
            T1 += __shfl_xor(T1, off, 16);
        }
        float n0 = __logf(S0) - __logf(T0);
        float n1 = __logf(S1) - __logf(T1);

        msg2[p * CC + lane] = pack_bf(n0, n1);

        atomicAdd(&agg[(long)d01.x * CC + lane], n0);
        atomicAdd(&agg[(long)d01.y * CC + lane], n1);
    }
}

// ---------------------------------------------------------------------------
// log_b = log_normalize(agg + log_b0); also resets agg for next iteration
// ---------------------------------------------------------------------------
__global__ __launch_bounds__(256) void k_update(
    const float* __restrict__ logb0, float* __restrict__ agg,
    float* __restrict__ out)
{
    int idx  = blockIdx.x * blockDim.x + threadIdx.x;
    int node = idx >> 4;
    if (node >= NN) return;
    float v = agg[idx] + logb0[idx];
    agg[idx] = 0.f;
    float m = v;
    for (int off = 8; off; off >>= 1) m = fmaxf(m, __shfl_xor(m, off, 16));
    float s = __expf(v - m);
    for (int off = 8; off; off >>= 1) s += __shfl_xor(s, off, 16);
    out[idx] = v - m - __logf(s);
}

// ---------------------------------------------------------------------------
extern "C" void kernel_launch(void* const* d_in, const int* in_sizes, int n_in,
                              void* d_out, int out_size, void* d_ws, size_t ws_size,
                              hipStream_t stream)
{
    const float* x     = (const float*)d_in[0];
    const float* W     = (const float*)d_in[1];
    const float* b     = (const float*)d_in[2];
    const float* param = (const float*)d_in[3];
    const int*   eidx  = (const int*)d_in[4];
    const int*   esrc  = eidx;
    const int*   edst  = eidx + EE;

    float* ws    = (float*)d_ws;
    float* M     = ws;                         // 256 floats
    float* logb0 = M     + 256;                // N*C
    float* logb  = logb0 + (long)NN * CC;      // N*C
    float* agg   = logb  + (long)NN * CC;      // N*C
    unsigned int* msg2 = (unsigned int*)(agg + (long)NN * CC);  // NPAIRS*C u32

    k_logb0<<<(NN * CC + 255) / 256, 256, 0, stream>>>(x, W, b, logb0);
    k_M    <<<1, 256, 0, stream>>>(param, M);
    k_init <<<2048, 256, 0, stream>>>(msg2, agg);

    const float* curb = logb0;
    for (int it = 0; it < NITERS; ++it) {
        k_edges<<<NGRP * 16 / 256, 256, 0, stream>>>(esrc, edst, curb, M, msg2, agg);
        float* dst = (it == NITERS - 1) ? (float*)d_out : logb;
        k_update<<<(NN * CC + 255) / 256, 256, 0, stream>>>(logb0, agg, dst);
        curb = dst;
    }
}

// Round 5
// 612.805 us; speedup vs baseline: 11.1907x; 1.0051x over previous
//
#include <hip/hip_runtime.h>
#include <math.h>

#define NN      100000
#define EE      1600000
#define NPAIRS  800000
#define DIN     128
#define CC      16
#define NITERS  5
#define PPT     4                    // pairs per thread
#define NGRP    (NPAIRS / PPT)       // 200000 groups of 16 lanes
#define NEGLOGC (-2.772588722239781f)

typedef float  f4 __attribute__((ext_vector_type(4)));
typedef int    i2 __attribute__((ext_vector_type(2)));

// ---------------------------------------------------------------------------
// helpers: bf16 <-> f32
// ---------------------------------------------------------------------------
__device__ __forceinline__ unsigned short f2bf(float f) {
    unsigned int u = __float_as_uint(f);
    unsigned int r = u + 0x7fffu + ((u >> 16) & 1u);   // round-nearest-even
    return (unsigned short)(r >> 16);
}
__device__ __forceinline__ unsigned int pack_bf(float lo, float hi) {
    return (unsigned int)f2bf(lo) | ((unsigned int)f2bf(hi) << 16);
}

// ---------------------------------------------------------------------------
// fused setup: M = sigmoid(10*param); logb0 = log_softmax(x@W+b); agg = 0
// grid = 6250 blocks of 256  (6250*256 == NN*CC exactly)
// ---------------------------------------------------------------------------
__global__ __launch_bounds__(256) void k_setup(
    const float* __restrict__ x, const float* __restrict__ W,
    const float* __restrict__ b, const float* __restrict__ param,
    float* __restrict__ M, float* __restrict__ logb0, float* __restrict__ agg)
{
    if (blockIdx.x == 0 && threadIdx.x < CC * (CC + 1) / 2) {
        int i = threadIdx.x;
        int r = 0;
        while ((r + 1) * (r + 2) / 2 <= i) ++r;
        int c = i - r * (r + 1) / 2;
        float z = param[i] * 10.0f;
        float s = 1.0f / (1.0f + __expf(-z));
        M[r * CC + c] = s;
        if (r != c) M[c * CC + r] = s;
    }

    int idx  = blockIdx.x * 256 + threadIdx.x;
    agg[idx] = 0.f;

    int node = idx >> 4;
    int cls  = idx & 15;
    const f4* xr4 = (const f4*)(x + (long)node * DIN);
    float acc = b[cls];
#pragma unroll 8
    for (int k4 = 0; k4 < DIN / 4; ++k4) {
        f4 xv = __builtin_nontemporal_load(xr4 + k4);   // x streamed once
        acc = fmaf(xv.x, W[(4 * k4 + 0) * CC + cls], acc);
        acc = fmaf(xv.y, W[(4 * k4 + 1) * CC + cls], acc);
        acc = fmaf(xv.z, W[(4 * k4 + 2) * CC + cls], acc);
        acc = fmaf(xv.w, W[(4 * k4 + 3) * CC + cls], acc);
    }
    float m = acc;
    for (int off = 8; off; off >>= 1) m = fmaxf(m, __shfl_xor(m, off, 16));
    float s = __expf(acc - m);
    for (int off = 8; off; off >>= 1) s += __shfl_xor(s, off, 16);
    logb0[idx] = acc - m - __logf(s);
}

// ---------------------------------------------------------------------------
// message update + scatter. 16 lanes per edge-pair (lane = class): coalesced
// msg I/O and coalesced 64B atomic scatter. Linear-space matvec:
//   S[c] = sum_k exp(t[k]) * M[k][c];  log_msg[c] = log S[c] - log(sum_c S[c])
// No max-subtraction needed: t in [-log C, ~7] -> exp fp32-safe, S >= ~6e-4.
// msg2[p*16+c] packs pair p both directions as bf16 {lo=edge 2p, hi=2p+1}.
// RD_MSG=false on iter 0 (msg == const -log C, never initialized in memory);
// WR_MSG=false on the last iter (msg never read again).
// Streamed arrays (msg2, esrc, edst) use non-temporal hints so the 4MiB/XCD
// L2 keeps agg (atomic RMW target) + logb (random gather) resident.
// Per-r private LDS staging slices -> the 4 pairs/thread software-pipeline.
// ---------------------------------------------------------------------------
template <bool RD_MSG, bool WR_MSG>
__global__ __launch_bounds__(256) void k_edges_t(
    const i2* __restrict__ esrc2, const i2* __restrict__ edst2,
    const float* __restrict__ logb, const float* __restrict__ Mg,
    unsigned int* __restrict__ msg2, float* __restrict__ agg)
{
    __shared__ float sM[CC * CC];
    __shared__ float sE[PPT][16 * 40];   // per-r slice, per-group stride 40
    sM[threadIdx.x] = Mg[threadIdx.x];   // blockDim == 256
    __syncthreads();

    const int lane = threadIdx.x & 15;
    const int gl   = threadIdx.x >> 4;           // group within block (0..15)
    const int g    = blockIdx.x * 16 + gl;       // global group

    float Hrow[CC];                              // M[k][lane] (symmetric)
#pragma unroll
    for (int k = 0; k < CC; ++k) Hrow[k] = sM[k * CC + lane];

    // hoist all streamed loads (independent -> deep pipelining)
    i2 s01[PPT], d01[PPT];
    unsigned int mold[PPT];
#pragma unroll
    for (int r = 0; r < PPT; ++r) {
        int p = g + r * NGRP;
        s01[r] = __builtin_nontemporal_load(esrc2 + p);
        d01[r] = __builtin_nontemporal_load(edst2 + p);
        if (RD_MSG)
            mold[r] = __builtin_nontemporal_load(msg2 + (long)p * CC + lane);
    }

    // exp(t) into per-r LDS slices
#pragma unroll
    for (int r = 0; r < PPT; ++r) {
        float lb0 = logb[(long)s01[r].x * CC + lane];
        float lb1 = logb[(long)s01[r].y * CC + lane];
        float mo0, mo1;
        if (RD_MSG) {
            mo0 = __uint_as_float(mold[r] << 16);          // msg[2p]
            mo1 = __uint_as_float(mold[r] & 0xffff0000u);  // msg[2p+1]
        } else {
            mo0 = NEGLOGC; mo1 = NEGLOGC;
        }
        float* eb = sE[r] + gl * 40;
        eb[lane]      = __expf(lb0 - mo1);   // t = logb[src] - msg[reverse]
        eb[16 + lane] = __expf(lb1 - mo0);
    }

    // matvec + normalize + store + scatter
#pragma unroll
    for (int r = 0; r < PPT; ++r) {
        const float* eb = sE[r] + gl * 40;
        float ev0[CC], ev1[CC];
        *(float4*)(ev0 +  0) = *(const float4*)(eb +  0);
        *(float4*)(ev0 +  4) = *(const float4*)(eb +  4);
        *(float4*)(ev0 +  8) = *(const float4*)(eb +  8);
        *(float4*)(ev0 + 12) = *(const float4*)(eb + 12);
        *(float4*)(ev1 +  0) = *(const float4*)(eb + 16);
        *(float4*)(ev1 +  4) = *(const float4*)(eb + 20);
        *(float4*)(ev1 +  8) = *(const float4*)(eb + 24);
        *(float4*)(ev1 + 12) = *(const float4*)(eb + 28);

        float S0 = 0.f, S1 = 0.f;
#pragma unroll
        for (int k = 0; k < CC; ++k) {
            S0 = fmaf(ev0[k], Hrow[k], S0);
            S1 = fmaf(ev1[k], Hrow[k], S1);
        }

        float T0 = S0, T1 = S1;
        for (int off = 8; off; off >>= 1) {
            T0 += __shfl_xor(T0, off, 16);
            T1 += __shfl_xor(T1, off, 16);
        }
        float n0 = __logf(S0) - __logf(T0);
        float n1 = __logf(S1) - __logf(T1);

        if (WR_MSG) {
            int p = g + r * NGRP;
            __builtin_nontemporal_store(pack_bf(n0, n1),
                                        msg2 + (long)p * CC + lane);
        }
        atomicAdd(&agg[(long)d01[r].x * CC + lane], n0);
        atomicAdd(&agg[(long)d01[r].y * CC + lane], n1);
    }
}

// ---------------------------------------------------------------------------
// log_b = log_normalize(agg + log_b0); also resets agg for next iteration
// ---------------------------------------------------------------------------
__global__ __launch_bounds__(256) void k_update(
    const float* __restrict__ logb0, float* __restrict__ agg,
    float* __restrict__ out)
{
    int idx = blockIdx.x * blockDim.x + threadIdx.x;
    float v = agg[idx] + logb0[idx];
    agg[idx] = 0.f;
    float m = v;
    for (int off = 8; off; off >>= 1) m = fmaxf(m, __shfl_xor(m, off, 16));
    float s = __expf(v - m);
    for (int off = 8; off; off >>= 1) s += __shfl_xor(s, off, 16);
    out[idx] = v - m - __logf(s);
}

// ---------------------------------------------------------------------------
extern "C" void kernel_launch(void* const* d_in, const int* in_sizes, int n_in,
                              void* d_out, int out_size, void* d_ws, size_t ws_size,
                              hipStream_t stream)
{
    const float* x     = (const float*)d_in[0];
    const float* W     = (const float*)d_in[1];
    const float* b     = (const float*)d_in[2];
    const float* param = (const float*)d_in[3];
    const int*   eidx  = (const int*)d_in[4];
    const i2*    esrc2 = (const i2*)eidx;
    const i2*    edst2 = (const i2*)(eidx + EE);

    float* ws    = (float*)d_ws;
    float* M     = ws;                         // 256 floats
    float* logb0 = M     + 256;                // N*C
    float* logb  = logb0 + (long)NN * CC;      // N*C
    float* agg   = logb  + (long)NN * CC;      // N*C
    unsigned int* msg2 = (unsigned int*)(agg + (long)NN * CC);  // NPAIRS*C u32

    k_setup<<<NN * CC / 256, 256, 0, stream>>>(x, W, b, param, M, logb0, agg);

    const float* curb = logb0;
    for (int it = 0; it < NITERS; ++it) {
        if (it == 0)
            k_edges_t<false, true><<<NGRP / 16, 256, 0, stream>>>(
                esrc2, edst2, curb, M, msg2, agg);
        else if (it == NITERS - 1)
            k_edges_t<true, false><<<NGRP / 16, 256, 0, stream>>>(
                esrc2, edst2, curb, M, msg2, agg);
        else
            k_edges_t<true, true><<<NGRP / 16, 256, 0, stream>>>(
                esrc2, edst2, curb, M, msg2, agg);
        float* dst = (it == NITERS - 1) ? (float*)d_out : logb;
        k_update<<<NN * CC / 256, 256, 0, stream>>>(logb0, agg, dst);
        curb = dst;
    }
}